// Round 9
// baseline (98.566 us; speedup 1.0000x reference)
//
#include <hip/hip_runtime.h>
#include <hip/hip_bf16.h>
#include <stdint.h>

// out[b,o,k] = sum_{h,m} W[o, h*64+m] * xl[b,h,k] * x0[b,m,k] + bias[o]
// B=256, M=H=64, K=128, OUT=256, C=4096.
// v9: direct GEMM out = W @ fmap with fmap B-frags built in REGISTERS
// (xl scalar x f32 x0 frags -> bf16 pack); all 16 MFMA/h accumulate straight
// into acc (AGPR) -- no VALU ever touches MFMA outputs inside the loop
// (v8's AGPR round-trip tax eliminated). v5-v8 skeleton kept: per-wave-
// private W staging via global_load_lds, 2-buf ring, counted vmcnt(8),
// no in-loop barriers. Wave tile o64 x n64; block = 4 waves (o256 x n64);
// grid (2 khalf, 256 b); LDS 80 KB -> 2 blocks/CU.

typedef __attribute__((ext_vector_type(8)))  short short8;
typedef __attribute__((ext_vector_type(16))) float f32x16;

#define B_SZ   256
#define K_SZ   128
#define OUT_SZ 256
#define C_SZ   4096
#define NH     64

__device__ __forceinline__ uint32_t pack_bf16(float a, float b) {
    __hip_bfloat162 h2 = __float22bfloat162_rn(make_float2(a, b));
    union { __hip_bfloat162 h; uint32_t u; } v;
    v.h = h2;
    return v.u;
}

__device__ __forceinline__ void load_lds_16(const void* g, void* l) {
    __builtin_amdgcn_global_load_lds(
        (const __attribute__((address_space(1))) unsigned int*)g,
        (__attribute__((address_space(3))) unsigned int*)l,
        16, 0, 0);
}

// ---- W f32 -> bf16 tiled for 32x32x16 A-frags (same layout as v4..v8) ----
// subtile = got*256 + cb16 (512 shorts, lane-linear):
//   element (o = got*32 + (lane&31), c = cb16*16 + (lane>>5)*8 + j)
__global__ void convert_W_tiled(const float* __restrict__ W, short* __restrict__ Wb) {
    int t = blockIdx.x * blockDim.x + threadIdx.x;   // 0..131071
    int lane = t & 63;
    int sub  = t >> 6;          // 0..2047
    int cb16 = sub & 255;
    int got  = sub >> 8;        // 0..7
    int o = got * 32 + (lane & 31);
    int c = cb16 * 16 + (lane >> 5) * 8;
    const float* p = W + (size_t)o * C_SZ + c;
    float4 w0 = *(const float4*)p;
    float4 w1 = *(const float4*)(p + 4);
    union { short8 s; uint32_t u[4]; } cc;
    cc.u[0] = pack_bf16(w0.x, w0.y);
    cc.u[1] = pack_bf16(w0.z, w0.w);
    cc.u[2] = pack_bf16(w1.x, w1.y);
    cc.u[3] = pack_bf16(w1.z, w1.w);
    *(short8*)(Wb + (size_t)t * 8) = cc.s;
}

template<bool USE_WS>
__global__ __launch_bounds__(256, 2)
void cin_main(const float* __restrict__ x0, const float* __restrict__ xl,
              const float* __restrict__ Wf, const short* __restrict__ Wb,
              const float* __restrict__ bias, float* __restrict__ out) {
    __shared__ short Wlds[2 * 4 * 4096];   // [buf][wave][4096 shorts] = 64 KB
    __shared__ float xlf[NH * 64];         // 16 KB f32 [h][k-half]

    const int b     = blockIdx.y;
    const int khalf = blockIdx.x;          // 0..1
    const int kb    = khalf * 64;
    const int tid   = threadIdx.x;
    const int lane  = tid & 63;
    const int wave  = tid >> 6;            // 0..3; wave owns o rows [64w, 64w+64)
    const int l31   = lane & 31;
    const int hi    = lane >> 5;

    // ---- stage this khalf of xl (f32, straight copy) into LDS ----
    {
        const float4* src = (const float4*)(xl + (size_t)b * (NH * K_SZ)
                                            + (tid >> 2) * K_SZ + kb + (tid & 3) * 16);
        float4* dst = (float4*)&xlf[(tid >> 2) * 64 + (tid & 3) * 16];
#pragma unroll
        for (int i = 0; i < 4; ++i) dst[i] = src[i];
    }

    // ---- x0 fragments as f32 (h-invariant): 64 VGPRs ----
    // x0f[cb][nt][j] = x0[m = cb*16 + hi*8 + j][n = kb + nt*32 + l31]
    float x0f[4][2][8];
    {
        const float* x0b = x0 + (size_t)b * (64 * K_SZ);
#pragma unroll
        for (int cb = 0; cb < 4; ++cb)
#pragma unroll
            for (int nt = 0; nt < 2; ++nt)
#pragma unroll
                for (int j = 0; j < 8; ++j)
                    x0f[cb][nt][j] = x0b[(cb * 16 + hi * 8 + j) * K_SZ + kb + nt * 32 + l31];
    }

    // ---- per-wave-private W staging (2-buf ring), 8 KB per wave per h ----
    // wave needs got = 2w (ot=0) and 2w+1 (ot=1), cb16 = 4h..4h+3 each.
    const short* wsrc0 = Wb + ((size_t)(2 * wave) * 256) * 512 + lane * 8;
    const short* wsrc1 = Wb + ((size_t)(2 * wave + 1) * 256) * 512 + lane * 8;
    const float* wfrow0 = Wf + (size_t)(2 * wave * 32 + l31) * C_SZ + hi * 8;
    const float* wfrow1 = wfrow0 + (size_t)32 * C_SZ;

    auto wlb = [&](int buf) { return Wlds + buf * 16384 + wave * 4096; };

    auto stage = [&](int buf, int h) {
        short* d = wlb(buf);
        if (USE_WS) {
            const short* s0 = wsrc0 + (size_t)(4 * h) * 512;
            const short* s1 = wsrc1 + (size_t)(4 * h) * 512;
#pragma unroll
            for (int cb = 0; cb < 4; ++cb)
                load_lds_16(s0 + cb * 512, d + cb * 512);
#pragma unroll
            for (int cb = 0; cb < 4; ++cb)
                load_lds_16(s1 + cb * 512, d + 2048 + cb * 512);
        } else {
#pragma unroll
            for (int ot = 0; ot < 2; ++ot) {
                const float* wf = ot ? wfrow1 : wfrow0;
#pragma unroll
                for (int cb = 0; cb < 4; ++cb) {
                    const float* p = wf + h * 64 + cb * 16;
                    float4 w0 = *(const float4*)p;
                    float4 w1 = *(const float4*)(p + 4);
                    union { short8 s; uint32_t u[4]; } cc;
                    cc.u[0] = pack_bf16(w0.x, w0.y);
                    cc.u[1] = pack_bf16(w0.z, w0.w);
                    cc.u[2] = pack_bf16(w1.x, w1.y);
                    cc.u[3] = pack_bf16(w1.z, w1.w);
                    *(short8*)(d + ot * 2048 + cb * 512 + lane * 8) = cc.s;
                }
            }
        }
    };

    f32x16 acc[2][2];
#pragma unroll
    for (int ot = 0; ot < 2; ++ot)
#pragma unroll
        for (int nt = 0; nt < 2; ++nt)
#pragma unroll
            for (int r = 0; r < 16; ++r) acc[ot][nt][r] = 0.f;

    // prologue: stage h=0 (buf0), h=1 (buf1); one barrier for xlf only
    stage(0, 0);
    stage(1, 1);
    __syncthreads();

    for (int h = 0; h < NH; ++h) {
        // wait for this h's 8 staged loads (h+1's 8 remain in flight)
        if (USE_WS) asm volatile("s_waitcnt vmcnt(8)" ::: "memory");

        const short* wb2 = wlb(h & 1) + lane * 8;
        short8 af[2][4];
#pragma unroll
        for (int ot = 0; ot < 2; ++ot)
#pragma unroll
            for (int cb = 0; cb < 4; ++cb)
                af[ot][cb] = *(const short8*)(wb2 + ot * 2048 + cb * 512);

        const float xlv0 = xlf[h * 64 + 0 * 32 + l31];
        const float xlv1 = xlf[h * 64 + 1 * 32 + l31];

        __builtin_amdgcn_s_setprio(1);
#pragma unroll
        for (int cb = 0; cb < 4; ++cb) {
            // B-frags: fmap[c = h*64 + cb*16 + hi*8 + j][n] = xl[h,n]*x0[m,n]
            union { short8 s; uint32_t u[4]; } b0, b1;
#pragma unroll
            for (int t2 = 0; t2 < 4; ++t2) {
                b0.u[t2] = pack_bf16(xlv0 * x0f[cb][0][2 * t2], xlv0 * x0f[cb][0][2 * t2 + 1]);
                b1.u[t2] = pack_bf16(xlv1 * x0f[cb][1][2 * t2], xlv1 * x0f[cb][1][2 * t2 + 1]);
            }
            acc[0][0] = __builtin_amdgcn_mfma_f32_32x32x16_bf16(af[0][cb], b0.s, acc[0][0], 0, 0, 0);
            acc[0][1] = __builtin_amdgcn_mfma_f32_32x32x16_bf16(af[0][cb], b1.s, acc[0][1], 0, 0, 0);
            acc[1][0] = __builtin_amdgcn_mfma_f32_32x32x16_bf16(af[1][cb], b0.s, acc[1][0], 0, 0, 0);
            acc[1][1] = __builtin_amdgcn_mfma_f32_32x32x16_bf16(af[1][cb], b1.s, acc[1][1], 0, 0, 0);
        }
        __builtin_amdgcn_s_setprio(0);

        // this h's ds_reads complete before overwriting buf (h&1)
        asm volatile("s_waitcnt lgkmcnt(0)" ::: "memory");
        stage(h & 1, (h + 2) & (NH - 1));
    }

    // ---- epilogue: bias + store ----
    // 32x32 C/D: col(k) = l31, row(o) = (r&3) + 8*(r>>2) + 4*hi   [m74/m101]
    float* outb = out + (size_t)b * (OUT_SZ * K_SZ);
#pragma unroll
    for (int ot = 0; ot < 2; ++ot) {
        const int obase = (2 * wave + ot) * 32;
#pragma unroll
        for (int r = 0; r < 16; ++r) {
            const int orow = obase + (r & 3) + 8 * (r >> 2) + 4 * hi;
            const float bv = bias[orow];
#pragma unroll
            for (int nt = 0; nt < 2; ++nt)
                outb[orow * K_SZ + kb + nt * 32 + l31] = acc[ot][nt][r] + bv;
        }
    }
}

extern "C" void kernel_launch(void* const* d_in, const int* in_sizes, int n_in,
                              void* d_out, int out_size, void* d_ws, size_t ws_size,
                              hipStream_t stream) {
    const float* x0   = (const float*)d_in[0];
    const float* xl   = (const float*)d_in[1];
    // d_in[2] is the scalar k (=128) — fixed by the problem shape
    const float* W    = (const float*)d_in[3];
    const float* bias = (const float*)d_in[4];
    float* out = (float*)d_out;

    const size_t w_bytes = (size_t)OUT_SZ * C_SZ * sizeof(short);
    short* Wb = (short*)d_ws;

    if (ws_size >= w_bytes) {
        convert_W_tiled<<<dim3(512), dim3(256), 0, stream>>>(W, Wb);
        cin_main<true><<<dim3(2, B_SZ), dim3(256), 0, stream>>>(x0, xl, W, Wb, bias, out);
    } else {
        cin_main<false><<<dim3(2, B_SZ), dim3(256), 0, stream>>>(x0, xl, W, Wb, bias, out);
    }
}

// Round 10
// 91.394 us; speedup vs baseline: 1.0785x; 1.0785x over previous
//
#include <hip/hip_runtime.h>
#include <hip/hip_bf16.h>
#include <stdint.h>

// out[b,o,k] = sum_{h,m} W[o, h*64+m] * xl[b,h,k] * x0[b,m,k] + bias[o]
// B=256, M=H=64, K=128, OUT=256, C=4096.
// v10: v9 skeleton (direct GEMM, register-built fmap B-frags, per-wave-private
// W staging via global_load_lds 2-buf ring, counted vmcnt(8), no in-loop
// barriers), datapath moved to F16:
//  - x0 frags pre-packed f16 pairs -> 32 VGPRs (was 64 f32; v9's AGPR-evict fix)
//  - xl staged in LDS as duplicated-f16 uint32 -> 1 ds_read_b32 = ready pk_mul operand
//  - B-frag build = 4 v_pk_mul_f16 (was 8 mul + 4 cvt_pk)
//  - mfma_f32_32x32x16_f16 (same rate as bf16), acc f32 in AGPR, VALU-untouched.

typedef __attribute__((ext_vector_type(8)))  short    short8;
typedef __attribute__((ext_vector_type(8)))  _Float16 f16x8;
typedef __attribute__((ext_vector_type(2)))  _Float16 h2v;
typedef __attribute__((ext_vector_type(16))) float    f32x16;

#define B_SZ   256
#define K_SZ   128
#define OUT_SZ 256
#define C_SZ   4096
#define NH     64

__device__ __forceinline__ uint32_t pack_f16(float a, float b) {
    union { h2v h; uint32_t u; } v;
    v.h = (h2v){(_Float16)a, (_Float16)b};
    return v.u;
}

__device__ __forceinline__ void load_lds_16(const void* g, void* l) {
    __builtin_amdgcn_global_load_lds(
        (const __attribute__((address_space(1))) unsigned int*)g,
        (__attribute__((address_space(3))) unsigned int*)l,
        16, 0, 0);
}

// ---- W f32 -> f16 tiled for 32x32x16 A-frags (same tiling as v4..v9) ----
// subtile = got*256 + cb16 (512 halves, lane-linear):
//   element (o = got*32 + (lane&31), c = cb16*16 + (lane>>5)*8 + j)
__global__ void convert_W_tiled(const float* __restrict__ W, short* __restrict__ Wb) {
    int t = blockIdx.x * blockDim.x + threadIdx.x;   // 0..131071
    int lane = t & 63;
    int sub  = t >> 6;          // 0..2047
    int cb16 = sub & 255;
    int got  = sub >> 8;        // 0..7
    int o = got * 32 + (lane & 31);
    int c = cb16 * 16 + (lane >> 5) * 8;
    const float* p = W + (size_t)o * C_SZ + c;
    float4 w0 = *(const float4*)p;
    float4 w1 = *(const float4*)(p + 4);
    union { short8 s; uint32_t u[4]; } cc;
    cc.u[0] = pack_f16(w0.x, w0.y);
    cc.u[1] = pack_f16(w0.z, w0.w);
    cc.u[2] = pack_f16(w1.x, w1.y);
    cc.u[3] = pack_f16(w1.z, w1.w);
    *(short8*)(Wb + (size_t)t * 8) = cc.s;
}

template<bool USE_WS>
__global__ __launch_bounds__(256, 2)
void cin_main(const float* __restrict__ x0, const float* __restrict__ xl,
              const float* __restrict__ Wf, const short* __restrict__ Wb,
              const float* __restrict__ bias, float* __restrict__ out) {
    __shared__ short    Wlds[2 * 4 * 4096];   // [buf][wave][4096 halves] = 64 KB
    __shared__ uint32_t xls[NH * 64];         // 16 KB: [h][k-half] dup-f16 pairs

    const int b     = blockIdx.y;
    const int khalf = blockIdx.x;          // 0..1
    const int kb    = khalf * 64;
    const int tid   = threadIdx.x;
    const int lane  = tid & 63;
    const int wave  = tid >> 6;            // 0..3; wave owns o rows [64w, 64w+64)
    const int l31   = lane & 31;
    const int hi    = lane >> 5;

    // ---- stage this khalf of xl as DUPLICATED f16 pairs into LDS ----
    {
        const int h    = tid >> 2;         // 0..63
        const int koff = (tid & 3) * 16;   // 0,16,32,48
        const float4* src = (const float4*)(xl + (size_t)b * (NH * K_SZ)
                                            + h * K_SZ + kb + koff);
        uint32_t* dst = &xls[h * 64 + koff];
#pragma unroll
        for (int i = 0; i < 4; ++i) {
            float4 v = src[i];
            dst[4 * i + 0] = pack_f16(v.x, v.x);
            dst[4 * i + 1] = pack_f16(v.y, v.y);
            dst[4 * i + 2] = pack_f16(v.z, v.z);
            dst[4 * i + 3] = pack_f16(v.w, v.w);
        }
    }

    // ---- x0 fragments packed f16 (h-invariant): 32 VGPRs ----
    // x0p[cb][nt].h[t] = f16{ x0[m=cb*16+hi*8+2t][n], x0[m=..+2t+1][n] },
    //   n = kb + nt*32 + l31
    union X0P { f16x8 v; h2v h[4]; uint32_t u[4]; } x0p[4][2];
    {
        const float* x0b = x0 + (size_t)b * (64 * K_SZ);
#pragma unroll
        for (int cb = 0; cb < 4; ++cb)
#pragma unroll
            for (int nt = 0; nt < 2; ++nt)
#pragma unroll
                for (int t2 = 0; t2 < 4; ++t2) {
                    const int m0 = cb * 16 + hi * 8 + 2 * t2;
                    const int cc = kb + nt * 32 + l31;
                    x0p[cb][nt].u[t2] = pack_f16(x0b[m0 * K_SZ + cc],
                                                 x0b[(m0 + 1) * K_SZ + cc]);
                }
    }

    // ---- per-wave-private W staging (2-buf ring), 8 KB per wave per h ----
    // wave needs got = 2w (ot=0) and 2w+1 (ot=1), cb16 = 4h..4h+3 each.
    const short* wsrc0 = Wb + ((size_t)(2 * wave) * 256) * 512 + lane * 8;
    const short* wsrc1 = Wb + ((size_t)(2 * wave + 1) * 256) * 512 + lane * 8;
    const float* wfrow0 = Wf + (size_t)(2 * wave * 32 + l31) * C_SZ + hi * 8;
    const float* wfrow1 = wfrow0 + (size_t)32 * C_SZ;

    auto wlb = [&](int buf) { return Wlds + buf * 16384 + wave * 4096; };

    auto stage = [&](int buf, int h) {
        short* d = wlb(buf);
        if (USE_WS) {
            const short* s0 = wsrc0 + (size_t)(4 * h) * 512;
            const short* s1 = wsrc1 + (size_t)(4 * h) * 512;
#pragma unroll
            for (int cb = 0; cb < 4; ++cb)
                load_lds_16(s0 + cb * 512, d + cb * 512);
#pragma unroll
            for (int cb = 0; cb < 4; ++cb)
                load_lds_16(s1 + cb * 512, d + 2048 + cb * 512);
        } else {
#pragma unroll
            for (int ot = 0; ot < 2; ++ot) {
                const float* wf = ot ? wfrow1 : wfrow0;
#pragma unroll
                for (int cb = 0; cb < 4; ++cb) {
                    const float* p = wf + h * 64 + cb * 16;
                    float4 w0 = *(const float4*)p;
                    float4 w1 = *(const float4*)(p + 4);
                    union { short8 s; uint32_t u[4]; } cc;
                    cc.u[0] = pack_f16(w0.x, w0.y);
                    cc.u[1] = pack_f16(w0.z, w0.w);
                    cc.u[2] = pack_f16(w1.x, w1.y);
                    cc.u[3] = pack_f16(w1.z, w1.w);
                    *(short8*)(d + ot * 2048 + cb * 512 + lane * 8) = cc.s;
                }
            }
        }
    };

    f32x16 acc[2][2];
#pragma unroll
    for (int ot = 0; ot < 2; ++ot)
#pragma unroll
        for (int nt = 0; nt < 2; ++nt)
#pragma unroll
            for (int r = 0; r < 16; ++r) acc[ot][nt][r] = 0.f;

    // prologue: stage h=0 (buf0), h=1 (buf1); one barrier (drains vmem too)
    stage(0, 0);
    stage(1, 1);
    __syncthreads();

    for (int h = 0; h < NH; ++h) {
        // wait for this h's 8 staged loads (h+1's 8 remain in flight)
        if (USE_WS) asm volatile("s_waitcnt vmcnt(8)" ::: "memory");

        const short* wb2 = wlb(h & 1) + lane * 8;
        f16x8 af[2][4];
#pragma unroll
        for (int ot = 0; ot < 2; ++ot)
#pragma unroll
            for (int cb = 0; cb < 4; ++cb)
                af[ot][cb] = *(const f16x8*)(wb2 + ot * 2048 + cb * 512);

        // duplicated-f16 xl multipliers (lane l and l+32 read same word)
        h2v xld0, xld1;
        { union { uint32_t u; h2v h; } t0, t1;
          t0.u = xls[h * 64 + 0 * 32 + l31];
          t1.u = xls[h * 64 + 1 * 32 + l31];
          xld0 = t0.h; xld1 = t1.h; }

        __builtin_amdgcn_s_setprio(1);
#pragma unroll
        for (int cb = 0; cb < 4; ++cb) {
            // B-frags: fmap[c = h*64 + cb*16 + hi*8 + j][n] = xl[h,n]*x0[m,n]
            union X0P b0, b1;
#pragma unroll
            for (int t2 = 0; t2 < 4; ++t2) {
                b0.h[t2] = xld0 * x0p[cb][0].h[t2];
                b1.h[t2] = xld1 * x0p[cb][1].h[t2];
            }
            acc[0][0] = __builtin_amdgcn_mfma_f32_32x32x16_f16(af[0][cb], b0.v, acc[0][0], 0, 0, 0);
            acc[0][1] = __builtin_amdgcn_mfma_f32_32x32x16_f16(af[0][cb], b1.v, acc[0][1], 0, 0, 0);
            acc[1][0] = __builtin_amdgcn_mfma_f32_32x32x16_f16(af[1][cb], b0.v, acc[1][0], 0, 0, 0);
            acc[1][1] = __builtin_amdgcn_mfma_f32_32x32x16_f16(af[1][cb], b1.v, acc[1][1], 0, 0, 0);
        }
        __builtin_amdgcn_s_setprio(0);

        // this h's ds_reads complete before overwriting buf (h&1)
        asm volatile("s_waitcnt lgkmcnt(0)" ::: "memory");
        stage(h & 1, (h + 2) & (NH - 1));
    }

    // ---- epilogue: bias + store ----
    // 32x32 C/D: col(k) = l31, row(o) = (r&3) + 8*(r>>2) + 4*hi   [m74/m101]
    float* outb = out + (size_t)b * (OUT_SZ * K_SZ);
#pragma unroll
    for (int ot = 0; ot < 2; ++ot) {
        const int obase = (2 * wave + ot) * 32;
#pragma unroll
        for (int r = 0; r < 16; ++r) {
            const int orow = obase + (r & 3) + 8 * (r >> 2) + 4 * hi;
            const float bv = bias[orow];
#pragma unroll
            for (int nt = 0; nt < 2; ++nt)
                outb[orow * K_SZ + kb + nt * 32 + l31] = acc[ot][nt][r] + bv;
        }
    }
}

extern "C" void kernel_launch(void* const* d_in, const int* in_sizes, int n_in,
                              void* d_out, int out_size, void* d_ws, size_t ws_size,
                              hipStream_t stream) {
    const float* x0   = (const float*)d_in[0];
    const float* xl   = (const float*)d_in[1];
    // d_in[2] is the scalar k (=128) — fixed by the problem shape
    const float* W    = (const float*)d_in[3];
    const float* bias = (const float*)d_in[4];
    float* out = (float*)d_out;

    const size_t w_bytes = (size_t)OUT_SZ * C_SZ * sizeof(short);
    short* Wb = (short*)d_ws;

    if (ws_size >= w_bytes) {
        convert_W_tiled<<<dim3(512), dim3(256), 0, stream>>>(W, Wb);
        cin_main<true><<<dim3(2, B_SZ), dim3(256), 0, stream>>>(x0, xl, W, Wb, bias, out);
    } else {
        cin_main<false><<<dim3(2, B_SZ), dim3(256), 0, stream>>>(x0, xl, W, Wb, bias, out);
    }
}

// Round 11
// 85.271 us; speedup vs baseline: 1.1559x; 1.0718x over previous
//
#include <hip/hip_runtime.h>
#include <hip/hip_bf16.h>
#include <stdint.h>

// out[b,o,k] = sum_{h,m} W[o, h*64+m] * xl[b,h,k] * x0[b,m,k] + bias[o]
// B=256, M=H=64, K=128, OUT=256, C=4096.
// v11: direct GEMM, f16 datapath (v10), W streamed global->REGISTER from the
// tiled Wb (no LDS for W, no barriers, no waitcnt asm): 4 coalesced
// global_load_dwordx4 per wave per h, ping-pong afA/afB, compiler-scheduled.
//  - grid (4 = ohalf x khalf, 256 b), 256 thr = 4 waves; wave owns o-tile
//    got = ohalf*4+wave (32 rows) x 64 k-cols (khalf). 16 waves/CU target.
//  - x0 frags f16-packed, h-invariant: 32 VGPR. xl dup-f16 in LDS (16 KB).
//  - B-build = 8 v_pk_mul_f16/h; 8 mfma_f32_32x32x16_f16 -> acc (32 AGPR),
//    VALU never touches acc.
//  - h-start rotated by b to decorrelate L2 access across blocks.

typedef __attribute__((ext_vector_type(8)))  short    short8;
typedef __attribute__((ext_vector_type(8)))  _Float16 f16x8;
typedef __attribute__((ext_vector_type(2)))  _Float16 h2v;
typedef __attribute__((ext_vector_type(16))) float    f32x16;

#define B_SZ   256
#define K_SZ   128
#define OUT_SZ 256
#define C_SZ   4096
#define NH     64

__device__ __forceinline__ uint32_t pack_f16(float a, float b) {
    union { h2v h; uint32_t u; } v;
    v.h = (h2v){(_Float16)a, (_Float16)b};
    return v.u;
}

// ---- W f32 -> f16 tiled for 32x32x16 A-frags (same tiling as v4..v10) ----
// subtile = got*256 + cb16 (512 halves, lane-linear):
//   element (o = got*32 + (lane&31), c = cb16*16 + (lane>>5)*8 + j)
__global__ void convert_W_tiled(const float* __restrict__ W, short* __restrict__ Wb) {
    int t = blockIdx.x * blockDim.x + threadIdx.x;   // 0..131071
    int lane = t & 63;
    int sub  = t >> 6;          // 0..2047
    int cb16 = sub & 255;
    int got  = sub >> 8;        // 0..7
    int o = got * 32 + (lane & 31);
    int c = cb16 * 16 + (lane >> 5) * 8;
    const float* p = W + (size_t)o * C_SZ + c;
    float4 w0 = *(const float4*)p;
    float4 w1 = *(const float4*)(p + 4);
    union { short8 s; uint32_t u[4]; } cc;
    cc.u[0] = pack_f16(w0.x, w0.y);
    cc.u[1] = pack_f16(w0.z, w0.w);
    cc.u[2] = pack_f16(w1.x, w1.y);
    cc.u[3] = pack_f16(w1.z, w1.w);
    *(short8*)(Wb + (size_t)t * 8) = cc.s;
}

template<bool USE_WS>
__global__ __launch_bounds__(256, 3)
void cin_main(const float* __restrict__ x0, const float* __restrict__ xl,
              const float* __restrict__ Wf, const short* __restrict__ Wb,
              const float* __restrict__ bias, float* __restrict__ out) {
    __shared__ uint32_t xls[NH * 64];      // 16 KB: [h][k-half col] dup-f16 pairs

    const int b     = blockIdx.y;
    const int bx    = blockIdx.x;          // 0..3
    const int ohalf = bx >> 1;
    const int khalf = bx & 1;
    const int kb    = khalf * 64;
    const int tid   = threadIdx.x;
    const int lane  = tid & 63;
    const int wave  = tid >> 6;            // 0..3
    const int got   = ohalf * 4 + wave;    // o-tile 0..7
    const int l31   = lane & 31;
    const int hi    = lane >> 5;

    // ---- stage this khalf of xl as DUPLICATED f16 pairs into LDS ----
    {
        const int h    = tid >> 2;         // 0..63
        const int koff = (tid & 3) * 16;   // 0,16,32,48
        const float4* src = (const float4*)(xl + (size_t)b * (NH * K_SZ)
                                            + h * K_SZ + kb + koff);
        uint32_t* dst = &xls[h * 64 + koff];
#pragma unroll
        for (int i = 0; i < 4; ++i) {
            float4 v = src[i];
            dst[4 * i + 0] = pack_f16(v.x, v.x);
            dst[4 * i + 1] = pack_f16(v.y, v.y);
            dst[4 * i + 2] = pack_f16(v.z, v.z);
            dst[4 * i + 3] = pack_f16(v.w, v.w);
        }
    }

    // ---- x0 fragments packed f16 (h-invariant): 32 VGPRs ----
    // x0p[cb][nt].h[t] = f16{ x0[m=cb*16+hi*8+2t][n], x0[m=..+2t+1][n] },
    //   n = kb + nt*32 + l31
    union X0P { f16x8 v; h2v h[4]; uint32_t u[4]; } x0p[4][2];
    {
        const float* x0b = x0 + (size_t)b * (64 * K_SZ);
#pragma unroll
        for (int cb = 0; cb < 4; ++cb)
#pragma unroll
            for (int nt = 0; nt < 2; ++nt)
#pragma unroll
                for (int t2 = 0; t2 < 4; ++t2) {
                    const int m0 = cb * 16 + hi * 8 + 2 * t2;
                    const int cc = kb + nt * 32 + l31;
                    x0p[cb][nt].u[t2] = pack_f16(x0b[m0 * K_SZ + cc],
                                                 x0b[(m0 + 1) * K_SZ + cc]);
                }
    }

    // ---- W streaming sources (per-wave A-frags, straight to registers) ----
    const short* wsrc  = Wb + ((size_t)got * 256) * 512 + (size_t)lane * 8;
    const float* wfrow = Wf + (size_t)(got * 32 + l31) * C_SZ + hi * 8;
    const int h0 = b & (NH - 1);           // per-block h rotation

    auto LOAD_AF = [&](f16x8* dst, int hh) {
        if (USE_WS) {
            const short* s0 = wsrc + (size_t)(4 * hh) * 512;
#pragma unroll
            for (int cb = 0; cb < 4; ++cb)
                dst[cb] = *(const f16x8*)(s0 + cb * 512);
        } else {
#pragma unroll
            for (int cb = 0; cb < 4; ++cb) {
                const float* p = wfrow + hh * 64 + cb * 16;
                float4 w0 = *(const float4*)p;
                float4 w1 = *(const float4*)(p + 4);
                union { f16x8 v; uint32_t u[4]; } cc;
                cc.u[0] = pack_f16(w0.x, w0.y);
                cc.u[1] = pack_f16(w0.z, w0.w);
                cc.u[2] = pack_f16(w1.x, w1.y);
                cc.u[3] = pack_f16(w1.z, w1.w);
                dst[cb] = cc.v;
            }
        }
    };

    f32x16 acc[2];
#pragma unroll
    for (int nt = 0; nt < 2; ++nt)
#pragma unroll
        for (int r = 0; r < 16; ++r) acc[nt][r] = 0.f;

    f16x8 afA[4], afB[4];
    LOAD_AF(afA, h0);
    LOAD_AF(afB, (h0 + 1) & (NH - 1));
    __syncthreads();                       // xls visible

#define COMPUTE(AF, HH)                                                              \
    do {                                                                             \
        const int h_ = (HH) & (NH - 1);                                              \
        h2v xld0, xld1;                                                              \
        { union { uint32_t u; h2v h; } t0, t1;                                       \
          t0.u = xls[h_ * 64 + 0 * 32 + l31];                                        \
          t1.u = xls[h_ * 64 + 1 * 32 + l31];                                        \
          xld0 = t0.h; xld1 = t1.h; }                                                \
        __builtin_amdgcn_s_setprio(1);                                               \
        _Pragma("unroll")                                                            \
        for (int cb = 0; cb < 4; ++cb) {                                             \
            union X0P b0, b1;                                                        \
            _Pragma("unroll")                                                        \
            for (int t2 = 0; t2 < 4; ++t2) {                                         \
                b0.h[t2] = xld0 * x0p[cb][0].h[t2];                                  \
                b1.h[t2] = xld1 * x0p[cb][1].h[t2];                                  \
            }                                                                        \
            acc[0] = __builtin_amdgcn_mfma_f32_32x32x16_f16(AF[cb], b0.v, acc[0], 0, 0, 0); \
            acc[1] = __builtin_amdgcn_mfma_f32_32x32x16_f16(AF[cb], b1.v, acc[1], 0, 0, 0); \
        }                                                                            \
        __builtin_amdgcn_s_setprio(0);                                               \
    } while (0)

    for (int i = 0; i < NH; i += 2) {
        COMPUTE(afA, h0 + i);
        LOAD_AF(afA, (h0 + i + 2) & (NH - 1));    // overlaps COMPUTE(afB)
        COMPUTE(afB, h0 + i + 1);
        LOAD_AF(afB, (h0 + i + 3) & (NH - 1));    // overlaps next COMPUTE(afA)
    }
#undef COMPUTE

    // ---- epilogue: bias + store ----
    // 32x32 C/D: col(k) = l31, row(o) = (r&3) + 8*(r>>2) + 4*hi   [m74/m101]
    float* outb = out + (size_t)b * (OUT_SZ * K_SZ);
#pragma unroll
    for (int r = 0; r < 16; ++r) {
        const int orow = got * 32 + (r & 3) + 8 * (r >> 2) + 4 * hi;
        const float bv = bias[orow];
#pragma unroll
        for (int nt = 0; nt < 2; ++nt)
            outb[orow * K_SZ + kb + nt * 32 + l31] = acc[nt][r] + bv;
    }
}

extern "C" void kernel_launch(void* const* d_in, const int* in_sizes, int n_in,
                              void* d_out, int out_size, void* d_ws, size_t ws_size,
                              hipStream_t stream) {
    const float* x0   = (const float*)d_in[0];
    const float* xl   = (const float*)d_in[1];
    // d_in[2] is the scalar k (=128) — fixed by the problem shape
    const float* W    = (const float*)d_in[3];
    const float* bias = (const float*)d_in[4];
    float* out = (float*)d_out;

    const size_t w_bytes = (size_t)OUT_SZ * C_SZ * sizeof(short);
    short* Wb = (short*)d_ws;

    if (ws_size >= w_bytes) {
        convert_W_tiled<<<dim3(512), dim3(256), 0, stream>>>(W, Wb);
        cin_main<true><<<dim3(4, B_SZ), dim3(256), 0, stream>>>(x0, xl, W, Wb, bias, out);
    } else {
        cin_main<false><<<dim3(4, B_SZ), dim3(256), 0, stream>>>(x0, xl, W, Wb, bias, out);
    }
}